// Round 3
// baseline (935.467 us; speedup 1.0000x reference)
//
#include <hip/hip_runtime.h>
#include <hip/hip_bf16.h>
#include <hip/hip_fp16.h>
#include <stdint.h>

typedef float    f32x4 __attribute__((ext_vector_type(4)));
typedef float    fvec4 __attribute__((ext_vector_type(4)));
typedef _Float16 f16x8 __attribute__((ext_vector_type(8)));

#define D_MODEL 1024
#define D_FF    4096
#define NTOK    8192
#define CAP_ROWS 17408   // 68 * 256 (expert regions 256-aligned)
#define NROWBLK  68

// ---- workspace layout (bytes) ----
#define OFF_WT  0UL            // 4*4096*1024*2 = 33,554,432 (shared W1^T then W2^T)
#define OFF_XG  33554432UL     // 17408*1024*2
#define OFF_H   69206016UL     // 17408*4096*2
#define OFF_CNT 211812352UL
#define OFF_CUR 211812368UL
#define OFF_OFS 211812384UL
#define OFF_TOK 211812416UL
#define OFF_WGT 211882048UL
#define OFF_E12 211951680UL
#define OFF_W12 211984448UL
#define WS_NEED 212049984UL

__device__ __forceinline__ void gload_lds16(const void* g, void* l) {
  __builtin_amdgcn_global_load_lds(
      (const __attribute__((address_space(1))) unsigned int*)g,
      (__attribute__((address_space(3))) unsigned int*)l, 16, 0, 0);
}

// ---------------- router ----------------
__global__ __launch_bounds__(256) void router_k(
    const float* __restrict__ x, const float* __restrict__ Wr,
    const float* __restrict__ br, int* __restrict__ counts,
    int* __restrict__ e12, float* __restrict__ w12) {
  int wid = threadIdx.x >> 6, lane = threadIdx.x & 63;
  int t = blockIdx.x * 4 + wid;
  const float* xr = x + (size_t)t * D_MODEL;
  float a0 = 0.f, a1 = 0.f, a2 = 0.f, a3 = 0.f;
#pragma unroll
  for (int c = 0; c < 4; ++c) {
    int d0 = c * 256 + lane * 4;
    fvec4 xv = *(const fvec4*)(xr + d0);
#pragma unroll
    for (int j = 0; j < 4; ++j) {
      fvec4 wv = *(const fvec4*)(Wr + (size_t)(d0 + j) * 4);
      a0 += xv[j] * wv[0]; a1 += xv[j] * wv[1];
      a2 += xv[j] * wv[2]; a3 += xv[j] * wv[3];
    }
  }
#pragma unroll
  for (int m = 32; m; m >>= 1) {
    a0 += __shfl_xor(a0, m, 64); a1 += __shfl_xor(a1, m, 64);
    a2 += __shfl_xor(a2, m, 64); a3 += __shfl_xor(a3, m, 64);
  }
  if (lane == 0) {
    float l[4] = {a0 + br[0], a1 + br[1], a2 + br[2], a3 + br[3]};
    int e1 = 0; float m1 = l[0];
#pragma unroll
    for (int e = 1; e < 4; ++e) if (l[e] > m1) { m1 = l[e]; e1 = e; }
    int e2 = -1; float m2 = -1e30f;
#pragma unroll
    for (int e = 0; e < 4; ++e) if (e != e1 && l[e] > m2) { m2 = l[e]; e2 = e; }
    float tt = expf(m2 - m1);
    float w1 = 1.f / (1.f + tt), w2 = tt / (1.f + tt);
    atomicAdd(&counts[e1], 1); atomicAdd(&counts[e2], 1);
    e12[t] = e1 | (e2 << 8);
    w12[2 * t] = w1; w12[2 * t + 1] = w2;
  }
}

// ---------------- prefix ----------------
__global__ void prefix_k(const int* __restrict__ counts, int* __restrict__ offs,
                         int* __restrict__ cursor) {
  if (threadIdx.x == 0 && blockIdx.x == 0) {
    int o = 0;
#pragma unroll
    for (int e = 0; e < 4; ++e) {
      offs[e] = o; cursor[e] = o;
      o += (counts[e] + 255) & ~255;
    }
    offs[4] = o;
  }
}

// ---------------- scatter lists ----------------
__global__ __launch_bounds__(256) void lists_k(
    const int* __restrict__ e12, const float* __restrict__ w12,
    int* __restrict__ cursor, int* __restrict__ tok, float* __restrict__ wgt) {
  int t = blockIdx.x * 256 + threadIdx.x;
  int p = e12[t];
  int e1 = p & 255, e2 = p >> 8;
  int i1 = atomicAdd(&cursor[e1], 1); tok[i1] = t; wgt[i1] = w12[2 * t];
  int i2 = atomicAdd(&cursor[e2], 1); tok[i2] = t; wgt[i2] = w12[2 * t + 1];
}

// ---------------- gather ----------------
__global__ __launch_bounds__(128) void gather_k(
    const float* __restrict__ x, const int* __restrict__ offs,
    const int* __restrict__ counts, const int* __restrict__ tok,
    _Float16* __restrict__ Xg) {
  int b = blockIdx.x;
  if (b >= offs[4]) return;
  int e = 0;
  while (e < 3 && b >= offs[e + 1]) ++e;
  int tid = threadIdx.x;
  f16x8 o;
  if (b < offs[e] + counts[e]) {
    int t = tok[b];
    const float* src = x + (size_t)t * D_MODEL + tid * 8;
    fvec4 v0 = *(const fvec4*)src;
    fvec4 v1 = *(const fvec4*)(src + 4);
#pragma unroll
    for (int j = 0; j < 4; ++j) { o[j] = (_Float16)v0[j]; o[4 + j] = (_Float16)v1[j]; }
  } else {
#pragma unroll
    for (int j = 0; j < 8; ++j) o[j] = (_Float16)0.f;
  }
  *(f16x8*)(Xg + (size_t)b * D_MODEL + tid * 8) = o;
}

// ---------------- transpose-convert weights ----------------
__global__ __launch_bounds__(256) void wtrans_k(
    const float* __restrict__ in, _Float16* __restrict__ out, int K, int N) {
  __shared__ float tile[64][65];
  int e = blockIdx.z;
  int n0 = blockIdx.x * 64, k0 = blockIdx.y * 64;
  const float* src = in + (size_t)e * K * N;
  _Float16* dst = out + (size_t)e * K * N;
  int t = threadIdx.x;
  {
    int kk = t >> 2, nc = (t & 3) * 16;
    const float* p = src + (size_t)(k0 + kk) * N + n0 + nc;
#pragma unroll
    for (int j = 0; j < 4; ++j) {
      fvec4 v = *(const fvec4*)(p + j * 4);
      tile[kk][nc + j * 4 + 0] = v[0]; tile[kk][nc + j * 4 + 1] = v[1];
      tile[kk][nc + j * 4 + 2] = v[2]; tile[kk][nc + j * 4 + 3] = v[3];
    }
  }
  __syncthreads();
  {
    int nn = t >> 2, kb = (t & 3) * 16;
    f16x8 o0, o1;
#pragma unroll
    for (int j = 0; j < 8; ++j) o0[j] = (_Float16)tile[kb + j][nn];
#pragma unroll
    for (int j = 0; j < 8; ++j) o1[j] = (_Float16)tile[kb + 8 + j][nn];
    _Float16* q = dst + (size_t)(n0 + nn) * K + k0 + kb;
    *(f16x8*)q = o0;
    *((f16x8*)q + 1) = o1;
  }
}

// ---------------- 8-phase / 2-K-tile 256x256 MFMA GEMM ----------------
// LDS 128KB: T0A@0 (A0,A1 16KB each), T1A@32K, T0B@64K (B0,B1), T1B@96K.
// Iteration computes K-tiles (2it)->T0 phases1-4, (2it+1)->T1 phases5-8.
// Stage ledger (verified liveness + vmcnt queue):
//  ph1: T1.B1<-t1   ph2: T1.A1<-t1   ph3: T0.A0<-t+2  ph4: T0.B0<-t+2
//  ph5: T0.B1<-t+2  ph6: T0.A1<-t+2  ph7: T1.A0<-t+3  ph8: T1.B0<-t+3
// vmcnt(8) at ends of ph1,2,4,5,6,8; all issue->wait distances 4-5 phases.

__device__ __forceinline__ f16x8 lds_frag(const char* base, int row, int kbyte) {
  return *(const f16x8*)(base + row * 128 + (kbyte ^ ((row & 7) << 4)));
}

template <int KD>
__device__ __forceinline__ void stage_ht(const _Float16* g0, int k0, char* lds, int tid) {
  int w = tid >> 6, l = tid & 63;
  int srow = l >> 3;
  int kx = (l & 7) ^ srow;                 // pre-swizzled global 16B chunk
  const _Float16* g = g0 + k0 + kx * 8;
#pragma unroll
  for (int j = 0; j < 2; ++j) {
    int c16 = j * 8 + w;
    gload_lds16(g + (size_t)(c16 * 8 + srow) * KD, lds + c16 * 1024);
  }
}

#define MFMA_QUAD(h, q, bf)                                                  \
  _Pragma("unroll") for (int m = 0; m < 4; ++m)                              \
  _Pragma("unroll") for (int n = 0; n < 2; ++n)                              \
  _Pragma("unroll") for (int kk = 0; kk < 2; ++kk)                           \
      acc[(h)*4 + m][(q)*2 + n] = __builtin_amdgcn_mfma_f32_16x16x32_f16(    \
          af[m*2 + kk], bf[n*2 + kk], acc[(h)*4 + m][(q)*2 + n], 0, 0, 0);

#define RDA(base)                                                            \
  _Pragma("unroll") for (int m = 0; m < 4; ++m)                              \
  _Pragma("unroll") for (int kk = 0; kk < 2; ++kk)                           \
      af[m*2 + kk] = lds_frag((base), wr*64 + m*16 + ln, kk*64 + kq);

#define RDB(dst, base)                                                       \
  _Pragma("unroll") for (int n = 0; n < 2; ++n)                              \
  _Pragma("unroll") for (int kk = 0; kk < 2; ++kk)                           \
      dst[n*2 + kk] = lds_frag((base), wc*32 + n*16 + ln, kk*64 + kq);

#define LGKM0 asm volatile("s_waitcnt lgkmcnt(0)" ::: "memory")
#define VM8   asm volatile("s_waitcnt vmcnt(8)" ::: "memory")
#define BAR   __builtin_amdgcn_s_barrier()
#define P1    __builtin_amdgcn_s_setprio(1)
#define P0    __builtin_amdgcn_s_setprio(0)

template <int KD, int MODE>
__global__ __launch_bounds__(512, 2) void gemm8_k(
    const _Float16* __restrict__ A, const _Float16* __restrict__ B,
    const float* __restrict__ bias, const int* __restrict__ offs,
    const int* __restrict__ counts, const int* __restrict__ tok,
    const float* __restrict__ wgt, _Float16* __restrict__ outH,
    float* __restrict__ outF, int NTOT) {
  extern __shared__ char smem[];
  // bijective XCD chunk swizzle over 1088 blocks (1088 % 8 == 0)
  int bid = blockIdx.x;
  int swz = (bid & 7) * 136 + (bid >> 3);
  int row = swz % NROWBLK;
  int cz  = swz / NROWBLK;
  int col, kz;
  if (MODE == 0) { col = cz; kz = 0; } else { col = cz & 3; kz = cz >> 2; }

  int rowBase = row * 256;
  if (rowBase >= offs[4]) return;
  int e = 0;
  while (e < 3 && rowBase >= offs[e + 1]) ++e;
  int eoff = offs[e], cnt = counts[e];
  if (rowBase >= eoff + cnt) return;
  int colBase = col * 256;
  int kbase = kz * 1024;

  int tid = threadIdx.x;
  int lane = tid & 63, wid = tid >> 6;
  int wr = wid >> 2, wc = wid & 3;
  int ln = lane & 15, kq = (lane >> 4) * 16;

  const _Float16* Ag = A + (size_t)rowBase * KD;
  const _Float16* Bg = B + (size_t)e * NTOT * KD + (size_t)colBase * KD;
  const _Float16* Ag1 = Ag + (size_t)128 * KD;
  const _Float16* Bg1 = Bg + (size_t)128 * KD;

  char* T0A = smem;
  char* T1A = smem + 32768;
  char* T0B = smem + 65536;
  char* T1B = smem + 98304;

  f32x4 acc[8][4];
  f32x4 zero = {0.f, 0.f, 0.f, 0.f};
#pragma unroll
  for (int i = 0; i < 8; ++i)
#pragma unroll
    for (int jn = 0; jn < 4; ++jn) acc[i][jn] = zero;

  const int NT = 16;           // K-tiles per block (both GEMMs: K=1024 here)
  const int ITER = NT / 2;

  // prologue: T0 <- tile0 (all 4 HT), T1 <- tile1 (A0,B0). vmcnt(8) retires T0.A0,B0.
  {
    int k0 = kbase, k1 = kbase + 64;
    stage_ht<KD>(Ag,  k0, T0A,          tid);
    stage_ht<KD>(Bg,  k0, T0B,          tid);
    stage_ht<KD>(Bg1, k0, T0B + 16384,  tid);
    stage_ht<KD>(Ag1, k0, T0A + 16384,  tid);
    stage_ht<KD>(Ag,  k1, T1A,          tid);
    stage_ht<KD>(Bg,  k1, T1B,          tid);
    VM8; BAR;
  }

  f16x8 af[8], bf0[4], bf1[4];

  for (int it = 0; it < ITER; ++it) {
    int k1 = kbase + (2 * it + 1) * 64;
    int t2 = 2 * it + 2; if (t2 > NT - 1) t2 = NT - 1;
    int t3 = 2 * it + 3; if (t3 > NT - 1) t3 = NT - 1;
    int k2 = kbase + t2 * 64, k3 = kbase + t3 * 64;

    // ph1: read T0.A0,T0.B0 ; stage T1.B1<-t1
    RDA(T0A); RDB(bf0, T0B);
    stage_ht<KD>(Bg1, k1, T1B + 16384, tid);
    BAR; LGKM0; P1; MFMA_QUAD(0, 0, bf0); P0; VM8; BAR;

    // ph2: read T0.B1 ; stage T1.A1<-t1
    RDB(bf1, T0B + 16384);
    stage_ht<KD>(Ag1, k1, T1A + 16384, tid);
    BAR; LGKM0; P1; MFMA_QUAD(0, 1, bf1); P0; VM8; BAR;

    // ph3: read T0.A1 ; stage T0.A0<-t2
    RDA(T0A + 16384);
    stage_ht<KD>(Ag, k2, T0A, tid);
    BAR; LGKM0; P1; MFMA_QUAD(1, 0, bf0); P0; BAR;

    // ph4: stage T0.B0<-t2
    stage_ht<KD>(Bg, k2, T0B, tid);
    BAR; LGKM0; P1; MFMA_QUAD(1, 1, bf1); P0; VM8; BAR;

    // ph5: read T1.A0,T1.B0 ; stage T0.B1<-t2
    RDA(T1A); RDB(bf0, T1B);
    stage_ht<KD>(Bg1, k2, T0B + 16384, tid);
    BAR; LGKM0; P1; MFMA_QUAD(0, 0, bf0); P0; VM8; BAR;

    // ph6: read T1.B1 ; stage T0.A1<-t2
    RDB(bf1, T1B + 16384);
    stage_ht<KD>(Ag1, k2, T0A + 16384, tid);
    BAR; LGKM0; P1; MFMA_QUAD(0, 1, bf1); P0; VM8; BAR;

    // ph7: read T1.A1 ; stage T1.A0<-t3
    RDA(T1A + 16384);
    stage_ht<KD>(Ag, k3, T1A, tid);
    BAR; LGKM0; P1; MFMA_QUAD(1, 0, bf0); P0; BAR;

    // ph8: stage T1.B0<-t3
    stage_ht<KD>(Bg, k3, T1B, tid);
    BAR; LGKM0; P1; MFMA_QUAD(1, 1, bf1); P0; VM8; BAR;
  }

  // ---- epilogue ----  C/D frag: col = lane&15, row = (lane>>4)*4 + j
  float bv[4];
#pragma unroll
  for (int q = 0; q < 2; ++q)
#pragma unroll
    for (int n = 0; n < 2; ++n)
      bv[q*2 + n] = bias[(size_t)e * NTOT + colBase + q*128 + wc*32 + n*16 + ln];

  if (MODE == 0) {
#pragma unroll
    for (int h = 0; h < 2; ++h)
#pragma unroll
      for (int m = 0; m < 4; ++m) {
        int rbase = rowBase + h*128 + wr*64 + m*16 + (lane >> 4) * 4;
#pragma unroll
        for (int j = 0; j < 4; ++j) {
          size_t ro = (size_t)(rbase + j) * NTOT;
#pragma unroll
          for (int q = 0; q < 2; ++q)
#pragma unroll
            for (int n = 0; n < 2; ++n) {
              float v = acc[h*4 + m][q*2 + n][j] + bv[q*2 + n];
              v = 0.5f * v * (1.f + erff(v * 0.70710678118654752f));
              outH[ro + colBase + q*128 + wc*32 + n*16 + ln] = (_Float16)v;
            }
        }
      }
  } else {
    float bq[4];
#pragma unroll
    for (int i = 0; i < 4; ++i) bq[i] = (kz == 0) ? bv[i] : 0.f;
#pragma unroll
    for (int h = 0; h < 2; ++h)
#pragma unroll
      for (int m = 0; m < 4; ++m) {
        int rbase = rowBase + h*128 + wr*64 + m*16 + (lane >> 4) * 4;
#pragma unroll
        for (int j = 0; j < 4; ++j) {
          int grow = rbase + j;
          if (grow - eoff < cnt) {
            int tkn = tok[grow];
            float w = wgt[grow];
            size_t o = (size_t)tkn * D_MODEL + colBase;
#pragma unroll
            for (int q = 0; q < 2; ++q)
#pragma unroll
              for (int n = 0; n < 2; ++n)
                atomicAdd(&outF[o + q*128 + wc*32 + n*16 + ln],
                          w * (acc[h*4 + m][q*2 + n][j] + bq[q*2 + n]));
          }
        }
      }
  }
}

extern "C" void kernel_launch(void* const* d_in, const int* in_sizes, int n_in,
                              void* d_out, int out_size, void* d_ws, size_t ws_size,
                              hipStream_t stream) {
  const float* x  = (const float*)d_in[0];
  const float* Wr = (const float*)d_in[1];
  const float* br = (const float*)d_in[2];
  const float* W1 = (const float*)d_in[3];
  const float* b1 = (const float*)d_in[4];
  const float* W2 = (const float*)d_in[5];
  const float* b2 = (const float*)d_in[6];
  float* out = (float*)d_out;
  char* ws = (char*)d_ws;
  if (ws_size < WS_NEED) return;

  _Float16* WT = (_Float16*)(ws + OFF_WT);
  _Float16* Xg = (_Float16*)(ws + OFF_XG);
  _Float16* H  = (_Float16*)(ws + OFF_H);
  int*   counts = (int*)(ws + OFF_CNT);
  int*   cursor = (int*)(ws + OFF_CUR);
  int*   offs   = (int*)(ws + OFF_OFS);
  int*   tok    = (int*)(ws + OFF_TOK);
  float* wgt    = (float*)(ws + OFF_WGT);
  int*   e12    = (int*)(ws + OFF_E12);
  float* w12    = (float*)(ws + OFF_W12);

  hipFuncSetAttribute((const void*)gemm8_k<1024, 0>,
                      hipFuncAttributeMaxDynamicSharedMemorySize, 131072);
  hipFuncSetAttribute((const void*)gemm8_k<4096, 1>,
                      hipFuncAttributeMaxDynamicSharedMemorySize, 131072);

  hipMemsetAsync(counts, 0, 16, stream);
  hipMemsetAsync(d_out, 0, (size_t)out_size * sizeof(float), stream);

  router_k<<<NTOK / 4, 256, 0, stream>>>(x, Wr, br, counts, e12, w12);
  prefix_k<<<1, 64, 0, stream>>>(counts, offs, cursor);
  lists_k<<<NTOK / 256, 256, 0, stream>>>(e12, w12, cursor, tok, wgt);
  gather_k<<<CAP_ROWS, 128, 0, stream>>>(x, offs, counts, tok, Xg);

  wtrans_k<<<dim3(64, 16, 4), 256, 0, stream>>>(W1, WT, 1024, 4096);
  gemm8_k<1024, 0><<<NROWBLK * 16, 512, 131072, stream>>>(
      Xg, WT, b1, offs, counts, tok, wgt, H, nullptr, D_FF);

  wtrans_k<<<dim3(16, 64, 4), 256, 0, stream>>>(W2, WT, 4096, 1024);
  gemm8_k<4096, 1><<<NROWBLK * 16, 512, 131072, stream>>>(
      H, WT, b2, offs, counts, tok, wgt, nullptr, out, D_MODEL);
}

// Round 4
// 779.193 us; speedup vs baseline: 1.2006x; 1.2006x over previous
//
#include <hip/hip_runtime.h>
#include <hip/hip_bf16.h>
#include <hip/hip_fp16.h>
#include <stdint.h>

typedef float    f32x4 __attribute__((ext_vector_type(4)));
typedef float    fvec4 __attribute__((ext_vector_type(4)));
typedef _Float16 f16x8 __attribute__((ext_vector_type(8)));

#define D_MODEL 1024
#define D_FF    4096
#define NTOK    8192
#define CAP_ROWS 16896  // 132 * 128
#define NRB      132    // row blocks of 128

// ---- workspace layout (bytes) ---- (identical to round-1, proven to fit)
#define OFF_W1  0UL           // 4*4096*1024*2 (W1^T fp16: [e][n][k])
#define OFF_W2  33554432UL    // 4*1024*4096*2 (W2^T fp16: [e][d][f])
#define OFF_XG  67108864UL    // 16896*1024*2
#define OFF_H   101711872UL   // 16896*4096*2
#define OFF_CNT 240123904UL
#define OFF_CUR 240123920UL
#define OFF_OFS 240123936UL
#define OFF_TOK 240124160UL
#define OFF_WGT 240191744UL
#define OFF_E12 240259328UL
#define OFF_W12 240292096UL
#define WS_NEED 240357632UL

__device__ __forceinline__ void gload_lds16(const void* g, void* l) {
  __builtin_amdgcn_global_load_lds(
      (const __attribute__((address_space(1))) unsigned int*)g,
      (__attribute__((address_space(3))) unsigned int*)l, 16, 0, 0);
}

// ---------------- router ----------------
__global__ __launch_bounds__(256) void router_k(
    const float* __restrict__ x, const float* __restrict__ Wr,
    const float* __restrict__ br, int* __restrict__ counts,
    int* __restrict__ e12, float* __restrict__ w12) {
  int wid = threadIdx.x >> 6, lane = threadIdx.x & 63;
  int t = blockIdx.x * 4 + wid;
  const float* xr = x + (size_t)t * D_MODEL;
  float a0 = 0.f, a1 = 0.f, a2 = 0.f, a3 = 0.f;
#pragma unroll
  for (int c = 0; c < 4; ++c) {
    int d0 = c * 256 + lane * 4;
    fvec4 xv = *(const fvec4*)(xr + d0);
#pragma unroll
    for (int j = 0; j < 4; ++j) {
      fvec4 wv = *(const fvec4*)(Wr + (size_t)(d0 + j) * 4);
      a0 += xv[j] * wv[0]; a1 += xv[j] * wv[1];
      a2 += xv[j] * wv[2]; a3 += xv[j] * wv[3];
    }
  }
#pragma unroll
  for (int m = 32; m; m >>= 1) {
    a0 += __shfl_xor(a0, m, 64); a1 += __shfl_xor(a1, m, 64);
    a2 += __shfl_xor(a2, m, 64); a3 += __shfl_xor(a3, m, 64);
  }
  if (lane == 0) {
    float l[4] = {a0 + br[0], a1 + br[1], a2 + br[2], a3 + br[3]};
    int e1 = 0; float m1 = l[0];
#pragma unroll
    for (int e = 1; e < 4; ++e) if (l[e] > m1) { m1 = l[e]; e1 = e; }
    int e2 = -1; float m2 = -1e30f;
#pragma unroll
    for (int e = 0; e < 4; ++e) if (e != e1 && l[e] > m2) { m2 = l[e]; e2 = e; }
    float tt = expf(m2 - m1);
    float w1 = 1.f / (1.f + tt), w2 = tt / (1.f + tt);
    atomicAdd(&counts[e1], 1); atomicAdd(&counts[e2], 1);
    e12[t] = e1 | (e2 << 8);
    w12[2 * t] = w1; w12[2 * t + 1] = w2;
  }
}

// ---------------- prefix: 128-aligned expert offsets ----------------
__global__ void prefix_k(const int* __restrict__ counts, int* __restrict__ offs,
                         int* __restrict__ cursor) {
  if (threadIdx.x == 0 && blockIdx.x == 0) {
    int o = 0;
#pragma unroll
    for (int e = 0; e < 4; ++e) {
      offs[e] = o; cursor[e] = o;
      o += (counts[e] + 127) & ~127;
    }
    offs[4] = o;
  }
}

// ---------------- scatter lists ----------------
__global__ __launch_bounds__(256) void lists_k(
    const int* __restrict__ e12, const float* __restrict__ w12,
    int* __restrict__ cursor, int* __restrict__ tok, float* __restrict__ wgt) {
  int t = blockIdx.x * 256 + threadIdx.x;
  int p = e12[t];
  int e1 = p & 255, e2 = p >> 8;
  int i1 = atomicAdd(&cursor[e1], 1); tok[i1] = t; wgt[i1] = w12[2 * t];
  int i2 = atomicAdd(&cursor[e2], 1); tok[i2] = t; wgt[i2] = w12[2 * t + 1];
}

// ---------------- gather ----------------
__global__ __launch_bounds__(128) void gather_k(
    const float* __restrict__ x, const int* __restrict__ offs,
    const int* __restrict__ counts, const int* __restrict__ tok,
    _Float16* __restrict__ Xg) {
  int b = blockIdx.x;
  if (b >= offs[4]) return;
  int e = 0;
  while (e < 3 && b >= offs[e + 1]) ++e;
  int tid = threadIdx.x;
  f16x8 o;
  if (b < offs[e] + counts[e]) {
    int t = tok[b];
    const float* src = x + (size_t)t * D_MODEL + tid * 8;
    fvec4 v0 = *(const fvec4*)src;
    fvec4 v1 = *(const fvec4*)(src + 4);
#pragma unroll
    for (int j = 0; j < 4; ++j) { o[j] = (_Float16)v0[j]; o[4 + j] = (_Float16)v1[j]; }
  } else {
#pragma unroll
    for (int j = 0; j < 8; ++j) o[j] = (_Float16)0.f;
  }
  *(f16x8*)(Xg + (size_t)b * D_MODEL + tid * 8) = o;
}

// ---------------- transpose-convert weights ----------------
__global__ __launch_bounds__(256) void wtrans_k(
    const float* __restrict__ in, _Float16* __restrict__ out, int K, int N) {
  __shared__ float tile[64][65];
  int e = blockIdx.z;
  int n0 = blockIdx.x * 64, k0 = blockIdx.y * 64;
  const float* src = in + (size_t)e * K * N;
  _Float16* dst = out + (size_t)e * K * N;
  int t = threadIdx.x;
  {
    int kk = t >> 2, nc = (t & 3) * 16;
    const float* p = src + (size_t)(k0 + kk) * N + n0 + nc;
#pragma unroll
    for (int j = 0; j < 4; ++j) {
      fvec4 v = *(const fvec4*)(p + j * 4);
      tile[kk][nc + j * 4 + 0] = v[0]; tile[kk][nc + j * 4 + 1] = v[1];
      tile[kk][nc + j * 4 + 2] = v[2]; tile[kk][nc + j * 4 + 3] = v[3];
    }
  }
  __syncthreads();
  {
    int nn = t >> 2, kb = (t & 3) * 16;
    f16x8 o0, o1;
#pragma unroll
    for (int j = 0; j < 8; ++j) o0[j] = (_Float16)tile[kb + j][nn];
#pragma unroll
    for (int j = 0; j < 8; ++j) o1[j] = (_Float16)tile[kb + 8 + j][nn];
    _Float16* q = dst + (size_t)(n0 + nn) * K + k0 + kb;
    *(f16x8*)q = o0;
    *((f16x8*)q + 1) = o1;
  }
}

// XOR-swizzled LDS fragment read (zero bank conflicts, proven r1)
__device__ __forceinline__ f16x8 lds_frag(const char* base, int row, int kbyte) {
  return *(const f16x8*)(base + row * 128 + (kbyte ^ ((row & 7) << 4)));
}

// ============ GEMM1: 128x256 tile, K=1024, gelu epilogue ============
// A: Xg [CAP_ROWS][1024]; B: W1^T [4][4096][1024]; out H [CAP_ROWS][4096] fp16.
// 4 waves (2x2), per-wave 64x128 out. LDS: A 16KB @0, B 32KB @16384. 2 blk/CU.
__global__ __launch_bounds__(256, 2) void gemm1_k(
    const _Float16* __restrict__ A, const _Float16* __restrict__ B,
    const float* __restrict__ bias, const int* __restrict__ offs,
    const int* __restrict__ counts, _Float16* __restrict__ outH) {
  __shared__ char lds[49152];
  // nwg = 132*16 = 2112; bijective XCD swizzle: q=264, r=0
  int bid = blockIdx.x;
  int wg = (bid & 7) * 264 + (bid >> 3);
  int col = wg & 15, row = wg >> 4;       // col-fastest: consecutive wg share A-panel
  int rowBase = row * 128;
  if (rowBase >= offs[4]) return;
  int e = 0;
  while (e < 3 && rowBase >= offs[e + 1]) ++e;
  if (rowBase >= offs[e] + counts[e]) return;
  int colBase = col * 256;

  int tid = threadIdx.x, wid = tid >> 6, lane = tid & 63;
  int wr = wid >> 1, wc = wid & 1;
  int ln = lane & 15;
  int srow = lane >> 3;
  int kx = (lane & 7) ^ srow;           // pre-swizzled global 16B chunk
  const _Float16* Abase = A + (size_t)rowBase * 1024 + kx * 8;
  const _Float16* Bbase = B + (size_t)e * D_FF * 1024 + (size_t)colBase * 1024 + kx * 8;
  char* ldsA = lds;
  char* ldsB = lds + 16384;

  f32x4 acc[4][8];
  f32x4 zero = {0.f, 0.f, 0.f, 0.f};
#pragma unroll
  for (int m = 0; m < 4; ++m)
#pragma unroll
    for (int n = 0; n < 8; ++n) acc[m][n] = zero;

  for (int k0 = 0; k0 < 1024; k0 += 64) {
#pragma unroll
    for (int i = 0; i < 4; ++i) {
      int chunk = wid * 4 + i;                 // 0..15 -> A rows 0..127
      gload_lds16(Abase + (size_t)(chunk * 8 + srow) * 1024 + k0, ldsA + chunk * 1024);
    }
#pragma unroll
    for (int i = 0; i < 8; ++i) {
      int chunk = wid * 8 + i;                 // 0..31 -> B rows 0..255
      gload_lds16(Bbase + (size_t)(chunk * 8 + srow) * 1024 + k0, ldsB + chunk * 1024);
    }
    __syncthreads();
#pragma unroll
    for (int kk = 0; kk < 2; ++kk) {
      int kbyte = kk * 64 + (lane >> 4) * 16;
      f16x8 af[4], bf[8];
#pragma unroll
      for (int m = 0; m < 4; ++m)
        af[m] = lds_frag(ldsA, wr * 64 + m * 16 + ln, kbyte);
#pragma unroll
      for (int n = 0; n < 8; ++n)
        bf[n] = lds_frag(ldsB, wc * 128 + n * 16 + ln, kbyte);
#pragma unroll
      for (int m = 0; m < 4; ++m)
#pragma unroll
        for (int n = 0; n < 8; ++n)
          acc[m][n] = __builtin_amdgcn_mfma_f32_16x16x32_f16(af[m], bf[n], acc[m][n], 0, 0, 0);
    }
    __syncthreads();
  }

  // epilogue: col = lane&15, row = (lane>>4)*4 + j
  int col0 = colBase + wc * 128 + ln;
  float bv[8];
#pragma unroll
  for (int n = 0; n < 8; ++n) bv[n] = bias[(size_t)e * D_FF + col0 + n * 16];
#pragma unroll
  for (int m = 0; m < 4; ++m) {
    int rbase = rowBase + wr * 64 + m * 16 + (lane >> 4) * 4;
#pragma unroll
    for (int j = 0; j < 4; ++j) {
      size_t ro = (size_t)(rbase + j) * D_FF;
#pragma unroll
      for (int n = 0; n < 8; ++n) {
        float v = acc[m][n][j] + bv[n];
        v = 0.5f * v * (1.f + erff(v * 0.70710678118654752f));
        outH[ro + col0 + n * 16] = (_Float16)v;
      }
    }
  }
}

// ============ GEMM2: 128x128 tile, K=4096, weighted-atomic epilogue ============
// A: H [CAP_ROWS][4096]; B: W2^T [4][1024][4096]; out: atomicAdd into out[tok][d].
// 4 waves (2x2), per-wave 64x64. LDS: A 16KB, B 16KB. 3 blk/CU.
__global__ __launch_bounds__(256, 3) void gemm2_k(
    const _Float16* __restrict__ A, const _Float16* __restrict__ B,
    const float* __restrict__ bias, const int* __restrict__ offs,
    const int* __restrict__ counts, const int* __restrict__ tok,
    const float* __restrict__ wgt, float* __restrict__ outF) {
  __shared__ char lds[32768];
  // nwg = 132*8 = 1056; bijective XCD swizzle: q=132, r=0
  int bid = blockIdx.x;
  int wg = (bid & 7) * 132 + (bid >> 3);
  int col = wg & 7, row = wg >> 3;        // col-fastest: consecutive wg share H-panel
  int rowBase = row * 128;
  if (rowBase >= offs[4]) return;
  int e = 0;
  while (e < 3 && rowBase >= offs[e + 1]) ++e;
  int eoff = offs[e], cnt = counts[e];
  if (rowBase >= eoff + cnt) return;
  int colBase = col * 128;

  int tid = threadIdx.x, wid = tid >> 6, lane = tid & 63;
  int wr = wid >> 1, wc = wid & 1;
  int ln = lane & 15;
  int srow = lane >> 3;
  int kx = (lane & 7) ^ srow;
  const _Float16* Abase = A + (size_t)rowBase * 4096 + kx * 8;
  const _Float16* Bbase = B + (size_t)e * D_MODEL * 4096 + (size_t)colBase * 4096 + kx * 8;
  char* ldsA = lds;
  char* ldsB = lds + 16384;

  f32x4 acc[4][4];
  f32x4 zero = {0.f, 0.f, 0.f, 0.f};
#pragma unroll
  for (int m = 0; m < 4; ++m)
#pragma unroll
    for (int n = 0; n < 4; ++n) acc[m][n] = zero;

  for (int k0 = 0; k0 < 4096; k0 += 64) {
#pragma unroll
    for (int i = 0; i < 4; ++i) {
      int chunk = wid * 4 + i;               // 0..15 -> 128 rows
      gload_lds16(Abase + (size_t)(chunk * 8 + srow) * 4096 + k0, ldsA + chunk * 1024);
      gload_lds16(Bbase + (size_t)(chunk * 8 + srow) * 4096 + k0, ldsB + chunk * 1024);
    }
    __syncthreads();
#pragma unroll
    for (int kk = 0; kk < 2; ++kk) {
      int kbyte = kk * 64 + (lane >> 4) * 16;
      f16x8 af[4], bf[4];
#pragma unroll
      for (int m = 0; m < 4; ++m)
        af[m] = lds_frag(ldsA, wr * 64 + m * 16 + ln, kbyte);
#pragma unroll
      for (int n = 0; n < 4; ++n)
        bf[n] = lds_frag(ldsB, wc * 64 + n * 16 + ln, kbyte);
#pragma unroll
      for (int m = 0; m < 4; ++m)
#pragma unroll
        for (int n = 0; n < 4; ++n)
          acc[m][n] = __builtin_amdgcn_mfma_f32_16x16x32_f16(af[m], bf[n], acc[m][n], 0, 0, 0);
    }
    __syncthreads();
  }

  int col0 = colBase + wc * 64 + ln;
  float bv[4];
#pragma unroll
  for (int n = 0; n < 4; ++n) bv[n] = bias[(size_t)e * D_MODEL + col0 + n * 16];
#pragma unroll
  for (int m = 0; m < 4; ++m) {
    int rbase = rowBase + wr * 64 + m * 16 + (lane >> 4) * 4;
#pragma unroll
    for (int j = 0; j < 4; ++j) {
      int grow = rbase + j;
      if (grow - eoff < cnt) {
        int t = tok[grow];
        float w = wgt[grow];
        size_t o = (size_t)t * D_MODEL + col0;
#pragma unroll
        for (int n = 0; n < 4; ++n)
          atomicAdd(&outF[o + n * 16], w * (acc[m][n][j] + bv[n]));
      }
    }
  }
}

extern "C" void kernel_launch(void* const* d_in, const int* in_sizes, int n_in,
                              void* d_out, int out_size, void* d_ws, size_t ws_size,
                              hipStream_t stream) {
  const float* x  = (const float*)d_in[0];
  const float* Wr = (const float*)d_in[1];
  const float* br = (const float*)d_in[2];
  const float* W1 = (const float*)d_in[3];
  const float* b1 = (const float*)d_in[4];
  const float* W2 = (const float*)d_in[5];
  const float* b2 = (const float*)d_in[6];
  float* out = (float*)d_out;
  char* ws = (char*)d_ws;
  if (ws_size < WS_NEED) return;

  _Float16* W1f = (_Float16*)(ws + OFF_W1);
  _Float16* W2f = (_Float16*)(ws + OFF_W2);
  _Float16* Xg  = (_Float16*)(ws + OFF_XG);
  _Float16* H   = (_Float16*)(ws + OFF_H);
  int*   counts = (int*)(ws + OFF_CNT);
  int*   cursor = (int*)(ws + OFF_CUR);
  int*   offs   = (int*)(ws + OFF_OFS);
  int*   tok    = (int*)(ws + OFF_TOK);
  float* wgt    = (float*)(ws + OFF_WGT);
  int*   e12    = (int*)(ws + OFF_E12);
  float* w12    = (float*)(ws + OFF_W12);

  hipMemsetAsync(counts, 0, 16, stream);
  hipMemsetAsync(d_out, 0, (size_t)out_size * sizeof(float), stream);

  router_k<<<NTOK / 4, 256, 0, stream>>>(x, Wr, br, counts, e12, w12);
  prefix_k<<<1, 64, 0, stream>>>(counts, offs, cursor);
  lists_k<<<NTOK / 256, 256, 0, stream>>>(e12, w12, cursor, tok, wgt);
  gather_k<<<CAP_ROWS, 128, 0, stream>>>(x, offs, counts, tok, Xg);
  wtrans_k<<<dim3(64, 16, 4), 256, 0, stream>>>(W1, W1f, 1024, 4096);
  wtrans_k<<<dim3(16, 64, 4), 256, 0, stream>>>(W2, W2f, 4096, 1024);

  gemm1_k<<<NRB * 16, 256, 0, stream>>>(Xg, W1f, b1, offs, counts, H);
  gemm2_k<<<NRB * 8, 256, 0, stream>>>(H, W2f, b2, offs, counts, tok, wgt, out);
}